// Round 13
// baseline (156.458 us; speedup 1.0000x reference)
//
#include <hip/hip_runtime.h>
#include <hip/hip_bf16.h>
#include <stdint.h>

typedef __bf16 bf16x8 __attribute__((ext_vector_type(8)));
typedef float  f32x4  __attribute__((ext_vector_type(4)));
typedef __hip_bfloat16 bf16;

// Geometry: B=4, Cin=1024, H=50, W=76, Cout=512, 3x3 pad=1; heads 18 + 36.
// M = 15200 (pad 15360 = 60*256), N = 512, K = 9216. NHWC padded features.

#define MROWS   15200
#define MTILES  119
#define KSTEPS  144      // 9216 / 64
#define NTK     72       // K-tiles per block (split-K=2)
#define HSLOT2  7864320  // 15360*512 elems per partial slot

__device__ __forceinline__ void gload16(const void* g, void* l) {
    __builtin_amdgcn_global_load_lds(
        (const __attribute__((address_space(1))) void*)(uintptr_t)g,
        (__attribute__((address_space(3))) void*)(uintptr_t)l,
        16, 0, 0);
}

// ======== merged preprocess: feat->NHWC | w_feat->bf16 | head weights | halo ========
__global__ __launch_bounds__(256) void preprocess(const float* __restrict__ features,
                                                  const float* __restrict__ w_feat,
                                                  const float* __restrict__ wo,
                                                  const float* __restrict__ wt,
                                                  bf16* __restrict__ feat_pad,
                                                  bf16* __restrict__ w2,
                                                  bf16* __restrict__ wh) {
    __shared__ float smem[128 * 77];           // 39.4 KB (feat tile / wmain row)
    const int blk = blockIdx.x;
    const int t = threadIdx.x;

    if (blk < 1600) {
        // ---- features NCHW fp32 -> padded NHWC bf16 (interior) ----
        float (*tile)[77] = (float (*)[77])smem;
        const int cb = blk & 7;
        const int by = blk >> 3;
        const int y = by % 50;
        const int b = by / 50;
        const float* s = features + (size_t)b * 3891200 + (size_t)(cb * 128) * 3800 + y * 76;
        for (int i = t; i < 128 * 76; i += 256) {
            int ci = i / 76, x = i - ci * 76;
            tile[ci][x] = s[ci * 3800 + x];
        }
        __syncthreads();
        bf16* d = feat_pad + ((size_t)(b * 52 + y + 1) * 78 + 1) * 1024 + cb * 128;
        for (int j = t; j < 76 * 128; j += 256) {
            int x = j >> 7, ci = j & 127;
            d[x * 1024 + ci] = __float2bfloat16(tile[ci][x]);
        }
    } else if (blk < 2112) {
        // ---- w_feat OIHW fp32 -> [co][(ky,kx,ci)] bf16 (LDS-tiled) ----
        const int co = blk - 1600;
        const float* s = w_feat + (size_t)co * 9216;
#pragma unroll
        for (int j = 0; j < 36; ++j) smem[t + j * 256] = s[t + j * 256];
        __syncthreads();
        bf16* d = w2 + (size_t)co * 9216;
#pragma unroll
        for (int j = 0; j < 36; ++j) {
            int o = t + j * 256;
            int k9 = o >> 10, ci = o & 1023;
            d[o] = __float2bfloat16(smem[ci * 9 + k9]);
        }
    } else if (blk < 2240) {
        // ---- head weights -> [n(64, pad)][512] bf16 ----
        int o = (blk - 2112) * 256 + t;        // < 64*512
        int n = o >> 9, ci = o & 511;
        float v = 0.f;
        if (n < 18)       v = wo[n * 512 + ci];
        else if (n < 54)  v = wt[(n - 18) * 512 + ci];
        wh[o] = __float2bfloat16(v);
    } else {
        // ---- zero only the halo of padded NHWC features ----
        const int tid = (blk - 2240) * 256 + t;   // < 131072
        const int chunk = tid & 127;
        const int cid = tid >> 7;                  // b*256 + e
        const int b = cid >> 8, e = cid & 255;
        int y, x;
        if (e < 156) { y = (e < 78) ? 0 : 51; x = (e < 78) ? e : e - 78; }
        else { int f = e - 156; x = (f < 50) ? 0 : 77; y = 1 + ((f < 50) ? f : f - 50); }
        bf16x8 z = {};
        *(bf16x8*)(feat_pad + (((size_t)(b * 52 + y) * 78 + x) << 10) + chunk * 8) = z;
    }
}

// ================= R13: R12 + s_setprio(1) around each MFMA cluster (T5 A/B) =================
// R12 created wave role diversity (un-phased: some waves staging/reading, some
// MFMA-ready) — T5's documented prerequisite (m218b: +21-39% with role split;
// m190: 0% lockstep). Single variable vs R12. Risk: setprio's side effects pin
// the ping-pong read-ahead (WAR distance 1 cluster, ~40-80cyc exposure);
// pre-committed read: positive -> keep, negative -> revert & declare plateau.

#define BARRIER() __builtin_amdgcn_s_barrier()
#define VM0()     asm volatile("s_waitcnt vmcnt(0)")

__global__ __launch_bounds__(512, 2) void conv_gemm8(const bf16* __restrict__ fp,
                                                     const bf16* __restrict__ w2,
                                                     bf16* __restrict__ hout) {
    __shared__ __attribute__((aligned(16))) bf16 lds[65536];   // 128 KB

    // XCD-aware bijective swizzle (240 = 8 XCD x 30)
    const int bid = (blockIdx.x & 7) * 30 + (blockIdx.x >> 3);
    const int mt = bid % 60;
    const int r3 = bid / 60;
    const int nt = r3 >> 1;
    const int sp = r3 & 1;
    const int ks0t = sp * NTK;                 // global K-tile base

    const int t = threadIdx.x;
    const int lane = t & 63, wid = t >> 6;
    const int wm = wid >> 2, wn = wid & 3;
    const int bHalf = wn >> 1;
    const int swz = ((t & 7) ^ ((t >> 3) & 7)) * 8;   // staging source k pre-swizzle

    const bf16* pA[2][2];
    const bf16* pB[2][2];
#pragma unroll
    for (int h = 0; h < 2; ++h)
#pragma unroll
        for (int j = 0; j < 2; ++j) {
            int m = mt * 256 + h * 128 + j * 64 + (t >> 3);
            if (m > MROWS - 1) m = MROWS - 1;
            int b = m / 3800, rr = m - b * 3800;
            int y = rr / 76, x = rr - y * 76;
            pA[h][j] = fp + (size_t)((b * 52 + y) * 78 + x) * 1024 + swz;
            int n = nt * 256 + h * 128 + j * 64 + (t >> 3);
            pB[h][j] = w2 + (size_t)n * 9216 + swz;
        }

#define STAGE_A(kts, h) do { \
        const int ko_ = (ks0t + (kts)) << 6; \
        const int k9_ = ko_ >> 10, ci0_ = ko_ & 1023; \
        const int ky_ = (k9_ * 11) >> 5, kx_ = k9_ - ky_ * 3; \
        const int aoff_ = ((ky_ * 78 + kx_) << 10) + ci0_; \
        bf16* d_ = lds + (((((kts) & 1) << 1) | (h)) << 13) + wid * 512; \
        gload16(pA[h][0] + aoff_, d_); \
        gload16(pA[h][1] + aoff_, d_ + 4096); \
    } while (0)

#define STAGE_B(kts, h) do { \
        const int ko_ = (ks0t + (kts)) << 6; \
        bf16* d_ = lds + 32768 + (((((kts) & 1) << 1) | (h)) << 13) + wid * 512; \
        gload16(pB[h][0] + ko_, d_); \
        gload16(pB[h][1] + ko_, d_ + 4096); \
    } while (0)

    const int aRowOff = (lane & 15) * 64;
    const int bRowOff = ((wn & 1) * 64 + (lane & 15)) * 64;
    const int sA0 = (((lane >> 4)    ) ^ (lane & 7)) * 8;   // kk=0 slot
    const int sA1 = (((lane >> 4) + 4) ^ (lane & 7)) * 8;   // kk=1 slot

    bf16x8 avA[2], avB[2], bvP[4];
    f32x4 acc[8][4];
#pragma unroll
    for (int i = 0; i < 8; ++i)
#pragma unroll
        for (int j = 0; j < 4; ++j) acc[i][j] = (f32x4){0.f, 0.f, 0.f, 0.f};

// load one quadrant's av pair (2 reads) for pass kk into register set S
#define LOAD_AVK(S, q, d, so) do { \
        const bf16* ab_ = lds + (((d) * 2 + wm) << 13) + (q) * 2048 + aRowOff; \
        S[0] = *(const bf16x8*)(ab_ + (so)); \
        S[1] = *(const bf16x8*)(ab_ + 1024 + (so)); \
    } while (0)

// load the 4 bv fragments (4 reads) for pass kk
#define LOAD_BVK(d, so) do { \
        const bf16* bb_ = lds + 32768 + (((d) * 2 + bHalf) << 13) + bRowOff; \
        bvP[0] = *(const bf16x8*)(bb_ + (so)); \
        bvP[1] = *(const bf16x8*)(bb_ + 1024 + (so)); \
        bvP[2] = *(const bf16x8*)(bb_ + 2048 + (so)); \
        bvP[3] = *(const bf16x8*)(bb_ + 3072 + (so)); \
    } while (0)

// one cluster: 8 MFMA (2 row-frags x 4 col-frags) for quadrant q, pass kk,
// wrapped in setprio (T5): MFMA-entering waves preempt stage/read-issuing ones.
#define MFMA8(q, S) do { \
        __builtin_amdgcn_s_setprio(1); \
        _Pragma("unroll") \
        for (int e_ = 0; e_ < 2; ++e_) \
        _Pragma("unroll") \
        for (int fn_ = 0; fn_ < 4; ++fn_) \
            acc[(q) * 2 + e_][fn_] = __builtin_amdgcn_mfma_f32_16x16x32_bf16( \
                S[e_], bvP[fn_], acc[(q) * 2 + e_][fn_], 0, 0, 0); \
        __builtin_amdgcn_s_setprio(0); \
    } while (0)

// One K-tile: stages under first reads' latency; two kk passes, av ping-pong;
// vmcnt(0) (free: DMA issued ~4000cyc earlier) + single boundary barrier.
#define TILE(kt, d) do { \
        const int s1_ = ((kt) + 1 < NTK) ? (kt) + 1 : 0;   /* tail: junk-but-safe */ \
        LOAD_BVK(d, sA0); LOAD_AVK(avA, 0, d, sA0); \
        STAGE_A(s1_, 0); STAGE_A(s1_, 1); \
        STAGE_B(s1_, 0); STAGE_B(s1_, 1); \
        LOAD_AVK(avB, 1, d, sA0); MFMA8(0, avA); \
        LOAD_AVK(avA, 2, d, sA0); MFMA8(1, avB); \
        LOAD_AVK(avB, 3, d, sA0); MFMA8(2, avA); \
        LOAD_AVK(avA, 0, d, sA1); MFMA8(3, avB); \
        LOAD_BVK(d, sA1); \
        LOAD_AVK(avB, 1, d, sA1); MFMA8(0, avA); \
        LOAD_AVK(avA, 2, d, sA1); MFMA8(1, avB); \
        LOAD_AVK(avB, 3, d, sA1); MFMA8(2, avA); \
                                  MFMA8(3, avB); \
        VM0(); BARRIER(); \
    } while (0)

    // -------- prologue: stage kt0 into buf0, land it --------
    STAGE_A(0, 0); STAGE_A(0, 1); STAGE_B(0, 0); STAGE_B(0, 1);
    VM0();
    BARRIER();

    // -------- main loop: 36 iterations x 2 K-tiles (static buf index) --------
    for (int i = 0; i < NTK / 2; ++i) {
        TILE(2 * i,     0);
        TILE(2 * i + 1, 1);
    }

    // -------- epilogue: raw bf16 partial -> slot sp --------
    const int mb = mt * 256 + wm * 128 + ((lane >> 4) << 2);
    const int nb = nt * 256 + wn * 64 + (lane & 15);
    bf16* hd = hout + (size_t)sp * HSLOT2;
#pragma unroll
    for (int fm = 0; fm < 8; ++fm) {
#pragma unroll
        for (int fn = 0; fn < 4; ++fn) {
#pragma unroll
            for (int jj = 0; jj < 4; ++jj) {
                int m = mb + fm * 16 + jj;
                if (m < MROWS)
                    hd[(size_t)m * 512 + nb + fn * 16] = __float2bfloat16(acc[fm][fn][jj]);
            }
        }
    }
}

// ---------------- fallback: 128x128 2-phase conv, RAW full-K partial -> slot 0 ----------------
__global__ __launch_bounds__(256) void conv_gemm1(const bf16* __restrict__ fp,
                                                  const bf16* __restrict__ w2,
                                                  bf16* __restrict__ hout) {
    __shared__ __attribute__((aligned(16))) bf16 Al[128 * 64];
    __shared__ __attribute__((aligned(16))) bf16 Bl[128 * 64];

    const int bid = blockIdx.x;
    const int mt = bid % MTILES;
    const int nt = bid / MTILES;
    const int t = threadIdx.x;
    const int lane = t & 63, wv = t >> 6;
    const int wr = wv >> 1, wc = wv & 1;
    const int kp8 = (((t & 7) ^ ((t >> 3) & 7))) * 8;

    const bf16* pA[4];
    const bf16* pB[4];
#pragma unroll
    for (int i = 0; i < 4; ++i) {
        int m = mt * 128 + i * 32 + (t >> 3);
        if (m > MROWS - 1) m = MROWS - 1;
        int b = m / 3800, r = m - b * 3800;
        int y = r / 76, x = r - y * 76;
        pA[i] = fp + (size_t)((b * 52 + y) * 78 + x) * 1024 + kp8;
        int n = nt * 128 + i * 32 + (t >> 3);
        pB[i] = w2 + (size_t)n * 9216 + kp8;
    }
    char* ldsA = (char*)Al + wv * 1024;
    char* ldsB = (char*)Bl + wv * 1024;

    f32x4 acc[4][4];
#pragma unroll
    for (int i = 0; i < 4; ++i)
#pragma unroll
        for (int j = 0; j < 4; ++j) acc[i][j] = (f32x4){0.f, 0.f, 0.f, 0.f};

    const bf16* aF = Al + (wr * 64 + (lane & 15)) * 64;
    const bf16* bF = Bl + (wc * 64 + (lane & 15)) * 64;
    const int so0 = (((lane >> 4)    ) ^ (lane & 7)) * 8;
    const int so1 = (((lane >> 4) + 4) ^ (lane & 7)) * 8;

    for (int ks = 0; ks < KSTEPS; ++ks) {
        const int ko = ks << 6;
        const int k9 = ko >> 10;
        const int ci0 = ko & 1023;
        const int ky = (k9 * 11) >> 5;
        const int kx = k9 - ky * 3;
        const int aoff = ((ky * 78 + kx) << 10) + ci0;
#pragma unroll
        for (int i = 0; i < 4; ++i) gload16(pA[i] + aoff, ldsA + i * 4096);
#pragma unroll
        for (int i = 0; i < 4; ++i) gload16(pB[i] + ko, ldsB + i * 4096);
        __syncthreads();
#pragma unroll
        for (int kk = 0; kk < 2; ++kk) {
            const int so = kk ? so1 : so0;
            bf16x8 av[4], bv[4];
#pragma unroll
            for (int f = 0; f < 4; ++f) av[f] = *(const bf16x8*)(aF + f * 1024 + so);
#pragma unroll
            for (int f = 0; f < 4; ++f) bv[f] = *(const bf16x8*)(bF + f * 1024 + so);
#pragma unroll
            for (int fm = 0; fm < 4; ++fm)
#pragma unroll
                for (int fn = 0; fn < 4; ++fn)
                    acc[fm][fn] = __builtin_amdgcn_mfma_f32_16x16x32_bf16(
                        av[fm], bv[fn], acc[fm][fn], 0, 0, 0);
        }
        __syncthreads();
    }

    const int mbase = mt * 128 + wr * 64 + ((lane >> 4) << 2);
    const int nbase = nt * 128 + wc * 64 + (lane & 15);
#pragma unroll
    for (int fn = 0; fn < 4; ++fn) {
        const int n = nbase + fn * 16;
#pragma unroll
        for (int fm = 0; fm < 4; ++fm) {
#pragma unroll
            for (int j = 0; j < 4; ++j) {
                int m = mbase + fm * 16 + j;
                if (m < MROWS)
                    hout[(size_t)m * 512 + n] = __float2bfloat16(acc[fm][fn][j]);
            }
        }
    }
}

// ---------------- 1x1 heads GEMM, fused partial-sum + bias + relu on A ----------------
// NSLOT=2: A = relu(p0 + p1 + b_feat);  NSLOT=1: A = relu(p0 + b_feat)
template<int NSLOT>
__global__ __launch_bounds__(256) void head_gemm(const bf16* __restrict__ p,
                                                 const bf16* __restrict__ wh,
                                                 const float* __restrict__ bfeat,
                                                 const float* __restrict__ bo,
                                                 const float* __restrict__ bt,
                                                 float* __restrict__ out) {
    __shared__ __attribute__((aligned(16))) bf16 Ah[2][128 * 64];  // dbuf, reg-staged
    __shared__ __attribute__((aligned(16))) bf16 Bh[64 * 512];

    const int mt = blockIdx.x;
    const int t = threadIdx.x;
    const int lane = t & 63, wv = t >> 6;
    const int s = t & 7;                       // k-slot 0..7
    const int rg = t >> 3;                     // row 0..31 within 32-row group

    {   // preload all head weights via async DMA (drained by first __syncthreads)
        char* lb = (char*)Bh + wv * 1024;
#pragma unroll
        for (int i = 0; i < 16; ++i) {
            const int row = i * 4 + wv;
            const bf16* src = wh + (size_t)row * 512 + (size_t)(lane ^ (row & 7)) * 8;
            gload16(src, lb + i * 4096);
        }
    }

    // A staging coords: rows m = mt*128 + i*32 + rg, logical k-chunk s
    size_t aoff[4];
#pragma unroll
    for (int i = 0; i < 4; ++i) {
        int m = mt * 128 + i * 32 + rg;
        if (m > MROWS - 1) m = MROWS - 1;
        aoff[i] = (size_t)m * 512 + s * 8;
    }
    const int wswz = (s ^ (rg & 7)) * 8;       // physical slot for ds_write

    f32x4 acc[2][4];
#pragma unroll
    for (int i = 0; i < 2; ++i)
#pragma unroll
        for (int j = 0; j < 4; ++j) acc[i][j] = (f32x4){0.f, 0.f, 0.f, 0.f};

    const bf16* bF = Bh + (lane & 15) * 512;
    const int so0 = (((lane >> 4)    ) ^ (lane & 7)) * 8;
    const int so1 = (((lane >> 4) + 4) ^ (lane & 7)) * 8;

    for (int ks = 0; ks < 8; ++ks) {
        const int ko = ks << 6;
        const int buf = ks & 1;
        // ---- reg-stage: load partials, sum + bias + relu, swizzled ds_write ----
        f32x4 b0 = *(const f32x4*)(bfeat + ko + s * 8);
        f32x4 b1 = *(const f32x4*)(bfeat + ko + s * 8 + 4);
#pragma unroll
        for (int i = 0; i < 4; ++i) {
            bf16x8 v0 = *(const bf16x8*)(p + aoff[i] + ko);
            bf16x8 r;
            if (NSLOT == 2) {
                bf16x8 v1 = *(const bf16x8*)(p + HSLOT2 + aoff[i] + ko);
#pragma unroll
                for (int j = 0; j < 8; ++j) {
                    float v = (float)v0[j] + (float)v1[j] + (j < 4 ? b0[j] : b1[j - 4]);
                    r[j] = (__bf16)(v < 0.f ? 0.f : v);
                }
            } else {
#pragma unroll
                for (int j = 0; j < 8; ++j) {
                    float v = (float)v0[j] + (j < 4 ? b0[j] : b1[j - 4]);
                    r[j] = (__bf16)(v < 0.f ? 0.f : v);
                }
            }
            *(bf16x8*)(&Ah[buf][(i * 32 + rg) * 64 + wswz]) = r;
        }
        __syncthreads();                       // writes visible; also drains Bh DMA on ks=0
        // ---- MFMA on buf ----
        const bf16* aF = &Ah[buf][(wv * 32 + (lane & 15)) * 64];
#pragma unroll
        for (int kk = 0; kk < 2; ++kk) {
            const int so = kk ? so1 : so0;
            bf16x8 av[2], bv[4];
#pragma unroll
            for (int f = 0; f < 2; ++f) av[f] = *(const bf16x8*)(aF + f * 1024 + so);
#pragma unroll
            for (int f = 0; f < 4; ++f) bv[f] = *(const bf16x8*)(bF + f * 8192 + ko + so);
#pragma unroll
            for (int fm = 0; fm < 2; ++fm)
#pragma unroll
                for (int fn = 0; fn < 4; ++fn)
                    acc[fm][fn] = __builtin_amdgcn_mfma_f32_16x16x32_bf16(
                        av[fm], bv[fn], acc[fm][fn], 0, 0, 0);
        }
    }

    // epilogue: out0[b*68400 + r*18 + n] (n<18), out1 at +273600: [b*136800 + r*36 + n-18]
#pragma unroll
    for (int fn = 0; fn < 4; ++fn) {
        const int n = fn * 16 + (lane & 15);
        if (n >= 54) continue;
        const float bb = (n < 18) ? bo[n] : bt[n - 18];
#pragma unroll
        for (int fm = 0; fm < 2; ++fm) {
#pragma unroll
            for (int j = 0; j < 4; ++j) {
                int m = mt * 128 + wv * 32 + fm * 16 + ((lane >> 4) << 2) + j;
                if (m < MROWS) {
                    int b = m / 3800, r = m - b * 3800;
                    float v = acc[fm][fn][j] + bb;
                    if (n < 18) out[(size_t)b * 68400 + r * 18 + n] = v;
                    else        out[273600 + (size_t)b * 136800 + r * 36 + (n - 18)] = v;
                }
            }
        }
    }
}

extern "C" void kernel_launch(void* const* d_in, const int* in_sizes, int n_in,
                              void* d_out, int out_size, void* d_ws, size_t ws_size,
                              hipStream_t stream) {
    const float* features = (const float*)d_in[0];
    const float* w_feat   = (const float*)d_in[1];
    const float* b_feat   = (const float*)d_in[2];
    const float* w_obj    = (const float*)d_in[3];
    const float* b_obj    = (const float*)d_in[4];
    const float* w_tr     = (const float*)d_in[5];
    const float* b_tr     = (const float*)d_in[6];
    float* out = (float*)d_out;

    char* ws = (char*)d_ws;
    bf16* feat_pad = (bf16*)(ws);              // 33,226,752 B
    bf16* w2       = (bf16*)(ws + 33226752);   //  9,437,184 B
    bf16* wh       = (bf16*)(ws + 42663936);   //     65,536 B
    bf16* hbuf     = (bf16*)(ws + 42729472);   // 2 slots x 15,728,640 B -> total 74,186,752 B

    preprocess<<<dim3(2752), dim3(256), 0, stream>>>(features, w_feat, w_obj, w_tr,
                                                     feat_pad, w2, wh);

    if (ws_size >= 74186752ull) {
        conv_gemm8<<<dim3(240), dim3(512), 0, stream>>>(feat_pad, w2, hbuf);
        head_gemm<2><<<dim3(MTILES), dim3(256), 0, stream>>>(hbuf, wh, b_feat, b_obj, b_tr, out);
    } else {
        conv_gemm1<<<dim3(MTILES * 4), dim3(256), 0, stream>>>(feat_pad, w2, hbuf);
        head_gemm<1><<<dim3(MTILES), dim3(256), 0, stream>>>(hbuf, wh, b_feat, b_obj, b_tr, out);
    }
}

// Round 14
// 152.294 us; speedup vs baseline: 1.0273x; 1.0273x over previous
//
#include <hip/hip_runtime.h>
#include <hip/hip_bf16.h>
#include <stdint.h>

typedef __bf16 bf16x8 __attribute__((ext_vector_type(8)));
typedef float  f32x4  __attribute__((ext_vector_type(4)));
typedef __hip_bfloat16 bf16;

// Geometry: B=4, Cin=1024, H=50, W=76, Cout=512, 3x3 pad=1; heads 18 + 36.
// M = 15200 (pad 15360 = 60*256), N = 512, K = 9216. NHWC padded features.

#define MROWS   15200
#define MTILES  119
#define MTILE2  238      // head_gemm: 64-row tiles (fills 238 of 256 CUs)
#define KSTEPS  144      // 9216 / 64
#define NTK     72       // K-tiles per block (split-K=2)
#define HSLOT2  7864320  // 15360*512 elems per partial slot

__device__ __forceinline__ void gload16(const void* g, void* l) {
    __builtin_amdgcn_global_load_lds(
        (const __attribute__((address_space(1))) void*)(uintptr_t)g,
        (__attribute__((address_space(3))) void*)(uintptr_t)l,
        16, 0, 0);
}

// ======== merged preprocess: feat->NHWC | w_feat->bf16 | head weights | halo ========
__global__ __launch_bounds__(256) void preprocess(const float* __restrict__ features,
                                                  const float* __restrict__ w_feat,
                                                  const float* __restrict__ wo,
                                                  const float* __restrict__ wt,
                                                  bf16* __restrict__ feat_pad,
                                                  bf16* __restrict__ w2,
                                                  bf16* __restrict__ wh) {
    __shared__ float smem[128 * 77];           // 39.4 KB (feat tile / wmain row)
    const int blk = blockIdx.x;
    const int t = threadIdx.x;

    if (blk < 1600) {
        // ---- features NCHW fp32 -> padded NHWC bf16 (interior) ----
        float (*tile)[77] = (float (*)[77])smem;
        const int cb = blk & 7;
        const int by = blk >> 3;
        const int y = by % 50;
        const int b = by / 50;
        const float* s = features + (size_t)b * 3891200 + (size_t)(cb * 128) * 3800 + y * 76;
        for (int i = t; i < 128 * 76; i += 256) {
            int ci = i / 76, x = i - ci * 76;
            tile[ci][x] = s[ci * 3800 + x];
        }
        __syncthreads();
        bf16* d = feat_pad + ((size_t)(b * 52 + y + 1) * 78 + 1) * 1024 + cb * 128;
        for (int j = t; j < 76 * 128; j += 256) {
            int x = j >> 7, ci = j & 127;
            d[x * 1024 + ci] = __float2bfloat16(tile[ci][x]);
        }
    } else if (blk < 2112) {
        // ---- w_feat OIHW fp32 -> [co][(ky,kx,ci)] bf16 (LDS-tiled) ----
        const int co = blk - 1600;
        const float* s = w_feat + (size_t)co * 9216;
#pragma unroll
        for (int j = 0; j < 36; ++j) smem[t + j * 256] = s[t + j * 256];
        __syncthreads();
        bf16* d = w2 + (size_t)co * 9216;
#pragma unroll
        for (int j = 0; j < 36; ++j) {
            int o = t + j * 256;
            int k9 = o >> 10, ci = o & 1023;
            d[o] = __float2bfloat16(smem[ci * 9 + k9]);
        }
    } else if (blk < 2240) {
        // ---- head weights -> [n(64, pad)][512] bf16 ----
        int o = (blk - 2112) * 256 + t;        // < 64*512
        int n = o >> 9, ci = o & 511;
        float v = 0.f;
        if (n < 18)       v = wo[n * 512 + ci];
        else if (n < 54)  v = wt[(n - 18) * 512 + ci];
        wh[o] = __float2bfloat16(v);
    } else {
        // ---- zero only the halo of padded NHWC features ----
        const int tid = (blk - 2240) * 256 + t;   // < 131072
        const int chunk = tid & 127;
        const int cid = tid >> 7;                  // b*256 + e
        const int b = cid >> 8, e = cid & 255;
        int y, x;
        if (e < 156) { y = (e < 78) ? 0 : 51; x = (e < 78) ? e : e - 78; }
        else { int f = e - 156; x = (f < 50) ? 0 : 77; y = 1 + ((f < 50) ? f : f - 50); }
        bf16x8 z = {};
        *(bf16x8*)(feat_pad + (((size_t)(b * 52 + y) * 78 + x) << 10) + chunk * 8) = z;
    }
}

// ================= R14 conv: R12-exact (best measured 134.3us) =================
// R13's setprio A/B was negative (-5%, pinned the ping-pong read-ahead) ->
// reverted. Probes ledger: 8-phase variants, 32x32 shape, 2-blocks/CU retile,
// read-hoist, barrier semantics, setprio all <= 0 vs this structure. 32x32
// conflict-free swizzle is provably impossible with linear gload_lds dests
// (rows = mod 8 share one of 8 slots -> 4-way). Remaining gap to MFMA floor
// (2483 vs 4481 cyc/K-tile) is asm-grade scheduling territory.

#define BARRIER() __builtin_amdgcn_s_barrier()
#define VM0()     asm volatile("s_waitcnt vmcnt(0)")

__global__ __launch_bounds__(512, 2) void conv_gemm8(const bf16* __restrict__ fp,
                                                     const bf16* __restrict__ w2,
                                                     bf16* __restrict__ hout) {
    __shared__ __attribute__((aligned(16))) bf16 lds[65536];   // 128 KB

    // XCD-aware bijective swizzle (240 = 8 XCD x 30)
    const int bid = (blockIdx.x & 7) * 30 + (blockIdx.x >> 3);
    const int mt = bid % 60;
    const int r3 = bid / 60;
    const int nt = r3 >> 1;
    const int sp = r3 & 1;
    const int ks0t = sp * NTK;                 // global K-tile base

    const int t = threadIdx.x;
    const int lane = t & 63, wid = t >> 6;
    const int wm = wid >> 2, wn = wid & 3;
    const int bHalf = wn >> 1;
    const int swz = ((t & 7) ^ ((t >> 3) & 7)) * 8;   // staging source k pre-swizzle

    const bf16* pA[2][2];
    const bf16* pB[2][2];
#pragma unroll
    for (int h = 0; h < 2; ++h)
#pragma unroll
        for (int j = 0; j < 2; ++j) {
            int m = mt * 256 + h * 128 + j * 64 + (t >> 3);
            if (m > MROWS - 1) m = MROWS - 1;
            int b = m / 3800, rr = m - b * 3800;
            int y = rr / 76, x = rr - y * 76;
            pA[h][j] = fp + (size_t)((b * 52 + y) * 78 + x) * 1024 + swz;
            int n = nt * 256 + h * 128 + j * 64 + (t >> 3);
            pB[h][j] = w2 + (size_t)n * 9216 + swz;
        }

#define STAGE_A(kts, h) do { \
        const int ko_ = (ks0t + (kts)) << 6; \
        const int k9_ = ko_ >> 10, ci0_ = ko_ & 1023; \
        const int ky_ = (k9_ * 11) >> 5, kx_ = k9_ - ky_ * 3; \
        const int aoff_ = ((ky_ * 78 + kx_) << 10) + ci0_; \
        bf16* d_ = lds + (((((kts) & 1) << 1) | (h)) << 13) + wid * 512; \
        gload16(pA[h][0] + aoff_, d_); \
        gload16(pA[h][1] + aoff_, d_ + 4096); \
    } while (0)

#define STAGE_B(kts, h) do { \
        const int ko_ = (ks0t + (kts)) << 6; \
        bf16* d_ = lds + 32768 + (((((kts) & 1) << 1) | (h)) << 13) + wid * 512; \
        gload16(pB[h][0] + ko_, d_); \
        gload16(pB[h][1] + ko_, d_ + 4096); \
    } while (0)

    const int aRowOff = (lane & 15) * 64;
    const int bRowOff = ((wn & 1) * 64 + (lane & 15)) * 64;
    const int sA0 = (((lane >> 4)    ) ^ (lane & 7)) * 8;   // kk=0 slot
    const int sA1 = (((lane >> 4) + 4) ^ (lane & 7)) * 8;   // kk=1 slot

    bf16x8 avA[2], avB[2], bvP[4];
    f32x4 acc[8][4];
#pragma unroll
    for (int i = 0; i < 8; ++i)
#pragma unroll
        for (int j = 0; j < 4; ++j) acc[i][j] = (f32x4){0.f, 0.f, 0.f, 0.f};

// load one quadrant's av pair (2 reads) for pass kk into register set S
#define LOAD_AVK(S, q, d, so) do { \
        const bf16* ab_ = lds + (((d) * 2 + wm) << 13) + (q) * 2048 + aRowOff; \
        S[0] = *(const bf16x8*)(ab_ + (so)); \
        S[1] = *(const bf16x8*)(ab_ + 1024 + (so)); \
    } while (0)

// load the 4 bv fragments (4 reads) for pass kk
#define LOAD_BVK(d, so) do { \
        const bf16* bb_ = lds + 32768 + (((d) * 2 + bHalf) << 13) + bRowOff; \
        bvP[0] = *(const bf16x8*)(bb_ + (so)); \
        bvP[1] = *(const bf16x8*)(bb_ + 1024 + (so)); \
        bvP[2] = *(const bf16x8*)(bb_ + 2048 + (so)); \
        bvP[3] = *(const bf16x8*)(bb_ + 3072 + (so)); \
    } while (0)

// one cluster: 8 MFMA (2 row-frags x 4 col-frags) for quadrant q, pass kk
#define MFMA8(q, S) do { \
        _Pragma("unroll") \
        for (int e_ = 0; e_ < 2; ++e_) \
        _Pragma("unroll") \
        for (int fn_ = 0; fn_ < 4; ++fn_) \
            acc[(q) * 2 + e_][fn_] = __builtin_amdgcn_mfma_f32_16x16x32_bf16( \
                S[e_], bvP[fn_], acc[(q) * 2 + e_][fn_], 0, 0, 0); \
    } while (0)

// One K-tile: stages under first reads' latency; two kk passes, av ping-pong;
// vmcnt(0) (free: DMA issued ~4000cyc earlier) + single boundary barrier.
#define TILE(kt, d) do { \
        const int s1_ = ((kt) + 1 < NTK) ? (kt) + 1 : 0;   /* tail: junk-but-safe */ \
        LOAD_BVK(d, sA0); LOAD_AVK(avA, 0, d, sA0); \
        STAGE_A(s1_, 0); STAGE_A(s1_, 1); \
        STAGE_B(s1_, 0); STAGE_B(s1_, 1); \
        LOAD_AVK(avB, 1, d, sA0); MFMA8(0, avA); \
        LOAD_AVK(avA, 2, d, sA0); MFMA8(1, avB); \
        LOAD_AVK(avB, 3, d, sA0); MFMA8(2, avA); \
        LOAD_AVK(avA, 0, d, sA1); MFMA8(3, avB); \
        LOAD_BVK(d, sA1); \
        LOAD_AVK(avB, 1, d, sA1); MFMA8(0, avA); \
        LOAD_AVK(avA, 2, d, sA1); MFMA8(1, avB); \
        LOAD_AVK(avB, 3, d, sA1); MFMA8(2, avA); \
                                  MFMA8(3, avB); \
        VM0(); BARRIER(); \
    } while (0)

    // -------- prologue: stage kt0 into buf0, land it --------
    STAGE_A(0, 0); STAGE_A(0, 1); STAGE_B(0, 0); STAGE_B(0, 1);
    VM0();
    BARRIER();

    // -------- main loop: 36 iterations x 2 K-tiles (static buf index) --------
    for (int i = 0; i < NTK / 2; ++i) {
        TILE(2 * i,     0);
        TILE(2 * i + 1, 1);
    }

    // -------- epilogue: raw bf16 partial -> slot sp --------
    const int mb = mt * 256 + wm * 128 + ((lane >> 4) << 2);
    const int nb = nt * 256 + wn * 64 + (lane & 15);
    bf16* hd = hout + (size_t)sp * HSLOT2;
#pragma unroll
    for (int fm = 0; fm < 8; ++fm) {
#pragma unroll
        for (int fn = 0; fn < 4; ++fn) {
#pragma unroll
            for (int jj = 0; jj < 4; ++jj) {
                int m = mb + fm * 16 + jj;
                if (m < MROWS)
                    hd[(size_t)m * 512 + nb + fn * 16] = __float2bfloat16(acc[fm][fn][jj]);
            }
        }
    }
}

// ---------------- fallback: 128x128 2-phase conv, RAW full-K partial -> slot 0 ----------------
__global__ __launch_bounds__(256) void conv_gemm1(const bf16* __restrict__ fp,
                                                  const bf16* __restrict__ w2,
                                                  bf16* __restrict__ hout) {
    __shared__ __attribute__((aligned(16))) bf16 Al[128 * 64];
    __shared__ __attribute__((aligned(16))) bf16 Bl[128 * 64];

    const int bid = blockIdx.x;
    const int mt = bid % MTILES;
    const int nt = bid / MTILES;
    const int t = threadIdx.x;
    const int lane = t & 63, wv = t >> 6;
    const int wr = wv >> 1, wc = wv & 1;
    const int kp8 = (((t & 7) ^ ((t >> 3) & 7))) * 8;

    const bf16* pA[4];
    const bf16* pB[4];
#pragma unroll
    for (int i = 0; i < 4; ++i) {
        int m = mt * 128 + i * 32 + (t >> 3);
        if (m > MROWS - 1) m = MROWS - 1;
        int b = m / 3800, r = m - b * 3800;
        int y = r / 76, x = r - y * 76;
        pA[i] = fp + (size_t)((b * 52 + y) * 78 + x) * 1024 + kp8;
        int n = nt * 128 + i * 32 + (t >> 3);
        pB[i] = w2 + (size_t)n * 9216 + kp8;
    }
    char* ldsA = (char*)Al + wv * 1024;
    char* ldsB = (char*)Bl + wv * 1024;

    f32x4 acc[4][4];
#pragma unroll
    for (int i = 0; i < 4; ++i)
#pragma unroll
        for (int j = 0; j < 4; ++j) acc[i][j] = (f32x4){0.f, 0.f, 0.f, 0.f};

    const bf16* aF = Al + (wr * 64 + (lane & 15)) * 64;
    const bf16* bF = Bl + (wc * 64 + (lane & 15)) * 64;
    const int so0 = (((lane >> 4)    ) ^ (lane & 7)) * 8;
    const int so1 = (((lane >> 4) + 4) ^ (lane & 7)) * 8;

    for (int ks = 0; ks < KSTEPS; ++ks) {
        const int ko = ks << 6;
        const int k9 = ko >> 10;
        const int ci0 = ko & 1023;
        const int ky = (k9 * 11) >> 5;
        const int kx = k9 - ky * 3;
        const int aoff = ((ky * 78 + kx) << 10) + ci0;
#pragma unroll
        for (int i = 0; i < 4; ++i) gload16(pA[i] + aoff, ldsA + i * 4096);
#pragma unroll
        for (int i = 0; i < 4; ++i) gload16(pB[i] + ko, ldsB + i * 4096);
        __syncthreads();
#pragma unroll
        for (int kk = 0; kk < 2; ++kk) {
            const int so = kk ? so1 : so0;
            bf16x8 av[4], bv[4];
#pragma unroll
            for (int f = 0; f < 4; ++f) av[f] = *(const bf16x8*)(aF + f * 1024 + so);
#pragma unroll
            for (int f = 0; f < 4; ++f) bv[f] = *(const bf16x8*)(bF + f * 1024 + so);
#pragma unroll
            for (int fm = 0; fm < 4; ++fm)
#pragma unroll
                for (int fn = 0; fn < 4; ++fn)
                    acc[fm][fn] = __builtin_amdgcn_mfma_f32_16x16x32_bf16(
                        av[fm], bv[fn], acc[fm][fn], 0, 0, 0);
        }
        __syncthreads();
    }

    const int mbase = mt * 128 + wr * 64 + ((lane >> 4) << 2);
    const int nbase = nt * 128 + wc * 64 + (lane & 15);
#pragma unroll
    for (int fn = 0; fn < 4; ++fn) {
        const int n = nbase + fn * 16;
#pragma unroll
        for (int fm = 0; fm < 4; ++fm) {
#pragma unroll
            for (int j = 0; j < 4; ++j) {
                int m = mbase + fm * 16 + j;
                if (m < MROWS)
                    hout[(size_t)m * 512 + n] = __float2bfloat16(acc[fm][fn][j]);
            }
        }
    }
}

// ---------------- 1x1 heads GEMM, fused partial-sum + bias + relu on A ----------------
// R14: 64-row tiles x 238 blocks (was 128x119 -> half the CUs idle), 128 thr.
// NSLOT=2: A = relu(p0 + p1 + b_feat);  NSLOT=1: A = relu(p0 + b_feat)
template<int NSLOT>
__global__ __launch_bounds__(128) void head_gemm(const bf16* __restrict__ p,
                                                 const bf16* __restrict__ wh,
                                                 const float* __restrict__ bfeat,
                                                 const float* __restrict__ bo,
                                                 const float* __restrict__ bt,
                                                 float* __restrict__ out) {
    __shared__ __attribute__((aligned(16))) bf16 Ah[2][64 * 64];   // dbuf, 16KB
    __shared__ __attribute__((aligned(16))) bf16 Bh[64 * 512];     // 64KB

    const int mt = blockIdx.x;                 // 238 tiles of 64 rows
    const int t = threadIdx.x;                 // 128 threads, 2 waves
    const int lane = t & 63, wv = t >> 6;
    const int s = t & 7;                       // k-slot 0..7
    const int rg = t >> 3;                     // row 0..15 within 16-row group

    {   // preload all head weights via async DMA: 2 waves x 32 rows (1 row/gload)
        char* lb = (char*)Bh + wv * 1024;
#pragma unroll
        for (int i = 0; i < 32; ++i) {
            const int row = i * 2 + wv;
            const bf16* src = wh + (size_t)row * 512 + (size_t)(lane ^ (row & 7)) * 8;
            gload16(src, lb + i * 2048);
        }
    }

    // A staging coords: rows m = mt*64 + i*16 + rg, logical k-chunk s
    size_t aoff[4];
#pragma unroll
    for (int i = 0; i < 4; ++i) {
        int m = mt * 64 + i * 16 + rg;
        if (m > MROWS - 1) m = MROWS - 1;
        aoff[i] = (size_t)m * 512 + s * 8;
    }
    const int wswz = (s ^ (rg & 7)) * 8;       // physical slot for ds_write

    f32x4 acc[2][4];
#pragma unroll
    for (int i = 0; i < 2; ++i)
#pragma unroll
        for (int j = 0; j < 4; ++j) acc[i][j] = (f32x4){0.f, 0.f, 0.f, 0.f};

    const bf16* bF = Bh + (lane & 15) * 512;
    const int so0 = (((lane >> 4)    ) ^ (lane & 7)) * 8;
    const int so1 = (((lane >> 4) + 4) ^ (lane & 7)) * 8;

    for (int ks = 0; ks < 8; ++ks) {
        const int ko = ks << 6;
        const int buf = ks & 1;
        // ---- reg-stage: load partials, sum + bias + relu, swizzled ds_write ----
        f32x4 b0 = *(const f32x4*)(bfeat + ko + s * 8);
        f32x4 b1 = *(const f32x4*)(bfeat + ko + s * 8 + 4);
#pragma unroll
        for (int i = 0; i < 4; ++i) {
            bf16x8 v0 = *(const bf16x8*)(p + aoff[i] + ko);
            bf16x8 r;
            if (NSLOT == 2) {
                bf16x8 v1 = *(const bf16x8*)(p + HSLOT2 + aoff[i] + ko);
#pragma unroll
                for (int j = 0; j < 8; ++j) {
                    float v = (float)v0[j] + (float)v1[j] + (j < 4 ? b0[j] : b1[j - 4]);
                    r[j] = (__bf16)(v < 0.f ? 0.f : v);
                }
            } else {
#pragma unroll
                for (int j = 0; j < 8; ++j) {
                    float v = (float)v0[j] + (j < 4 ? b0[j] : b1[j - 4]);
                    r[j] = (__bf16)(v < 0.f ? 0.f : v);
                }
            }
            *(bf16x8*)(&Ah[buf][(i * 16 + rg) * 64 + wswz]) = r;
        }
        __syncthreads();                       // writes visible; also drains Bh DMA on ks=0
        // ---- MFMA on buf ----
        const bf16* aF = &Ah[buf][(wv * 32 + (lane & 15)) * 64];
#pragma unroll
        for (int kk = 0; kk < 2; ++kk) {
            const int so = kk ? so1 : so0;
            bf16x8 av[2], bv[4];
#pragma unroll
            for (int f = 0; f < 2; ++f) av[f] = *(const bf16x8*)(aF + f * 1024 + so);
#pragma unroll
            for (int f = 0; f < 4; ++f) bv[f] = *(const bf16x8*)(bF + f * 8192 + ko + so);
#pragma unroll
            for (int fm = 0; fm < 2; ++fm)
#pragma unroll
                for (int fn = 0; fn < 4; ++fn)
                    acc[fm][fn] = __builtin_amdgcn_mfma_f32_16x16x32_bf16(
                        av[fm], bv[fn], acc[fm][fn], 0, 0, 0);
        }
    }

    // epilogue: out0[b*68400 + r*18 + n] (n<18), out1 at +273600: [b*136800 + r*36 + n-18]
#pragma unroll
    for (int fn = 0; fn < 4; ++fn) {
        const int n = fn * 16 + (lane & 15);
        if (n >= 54) continue;
        const float bb = (n < 18) ? bo[n] : bt[n - 18];
#pragma unroll
        for (int fm = 0; fm < 2; ++fm) {
#pragma unroll
            for (int j = 0; j < 4; ++j) {
                int m = mt * 64 + wv * 32 + fm * 16 + ((lane >> 4) << 2) + j;
                if (m < MROWS) {
                    int b = m / 3800, r = m - b * 3800;
                    float v = acc[fm][fn][j] + bb;
                    if (n < 18) out[(size_t)b * 68400 + r * 18 + n] = v;
                    else        out[273600 + (size_t)b * 136800 + r * 36 + (n - 18)] = v;
                }
            }
        }
    }
}

extern "C" void kernel_launch(void* const* d_in, const int* in_sizes, int n_in,
                              void* d_out, int out_size, void* d_ws, size_t ws_size,
                              hipStream_t stream) {
    const float* features = (const float*)d_in[0];
    const float* w_feat   = (const float*)d_in[1];
    const float* b_feat   = (const float*)d_in[2];
    const float* w_obj    = (const float*)d_in[3];
    const float* b_obj    = (const float*)d_in[4];
    const float* w_tr     = (const float*)d_in[5];
    const float* b_tr     = (const float*)d_in[6];
    float* out = (float*)d_out;

    char* ws = (char*)d_ws;
    bf16* feat_pad = (bf16*)(ws);              // 33,226,752 B
    bf16* w2       = (bf16*)(ws + 33226752);   //  9,437,184 B
    bf16* wh       = (bf16*)(ws + 42663936);   //     65,536 B
    bf16* hbuf     = (bf16*)(ws + 42729472);   // 2 slots x 15,728,640 B -> total 74,186,752 B

    preprocess<<<dim3(2752), dim3(256), 0, stream>>>(features, w_feat, w_obj, w_tr,
                                                     feat_pad, w2, wh);

    if (ws_size >= 74186752ull) {
        conv_gemm8<<<dim3(240), dim3(512), 0, stream>>>(feat_pad, w2, hbuf);
        head_gemm<2><<<dim3(MTILE2), dim3(128), 0, stream>>>(hbuf, wh, b_feat, b_obj, b_tr, out);
    } else {
        conv_gemm1<<<dim3(MTILES * 4), dim3(256), 0, stream>>>(feat_pad, w2, hbuf);
        head_gemm<1><<<dim3(MTILE2), dim3(128), 0, stream>>>(hbuf, wh, b_feat, b_obj, b_tr, out);
    }
}

// Round 15
// 151.912 us; speedup vs baseline: 1.0299x; 1.0025x over previous
//
#include <hip/hip_runtime.h>
#include <hip/hip_bf16.h>
#include <stdint.h>

typedef __bf16 bf16x8 __attribute__((ext_vector_type(8)));
typedef float  f32x4  __attribute__((ext_vector_type(4)));
typedef __hip_bfloat16 bf16;

// Geometry: B=4, Cin=1024, H=50, W=76, Cout=512, 3x3 pad=1; heads 18 + 36.
// M = 15200 (pad 15360 = 60*256), N = 512, K = 9216. NHWC padded features.

#define MROWS   15200
#define MTILES  119
#define MTILE2  238      // head_gemm: 64-row tiles (fills 238 of 256 CUs)
#define KSTEPS  144      // 9216 / 64
#define NTK     72       // K-tiles per block (split-K=2)
#define HSLOT2  7864320  // 15360*512 elems per partial slot

__device__ __forceinline__ void gload16(const void* g, void* l) {
    __builtin_amdgcn_global_load_lds(
        (const __attribute__((address_space(1))) void*)(uintptr_t)g,
        (__attribute__((address_space(3))) void*)(uintptr_t)l,
        16, 0, 0);
}

// ======== merged preprocess: feat->NHWC | w_feat->bf16 | head weights | halo ========
__global__ __launch_bounds__(256) void preprocess(const float* __restrict__ features,
                                                  const float* __restrict__ w_feat,
                                                  const float* __restrict__ wo,
                                                  const float* __restrict__ wt,
                                                  bf16* __restrict__ feat_pad,
                                                  bf16* __restrict__ w2,
                                                  bf16* __restrict__ wh) {
    __shared__ float smem[128 * 77];           // 39.4 KB (feat tile / wmain row)
    const int blk = blockIdx.x;
    const int t = threadIdx.x;

    if (blk < 1600) {
        // ---- features NCHW fp32 -> padded NHWC bf16 (interior) ----
        float (*tile)[77] = (float (*)[77])smem;
        const int cb = blk & 7;
        const int by = blk >> 3;
        const int y = by % 50;
        const int b = by / 50;
        const float* s = features + (size_t)b * 3891200 + (size_t)(cb * 128) * 3800 + y * 76;
        for (int i = t; i < 128 * 76; i += 256) {
            int ci = i / 76, x = i - ci * 76;
            tile[ci][x] = s[ci * 3800 + x];
        }
        __syncthreads();
        bf16* d = feat_pad + ((size_t)(b * 52 + y + 1) * 78 + 1) * 1024 + cb * 128;
        for (int j = t; j < 76 * 128; j += 256) {
            int x = j >> 7, ci = j & 127;
            d[x * 1024 + ci] = __float2bfloat16(tile[ci][x]);
        }
    } else if (blk < 2112) {
        // ---- w_feat OIHW fp32 -> [co][(ky,kx,ci)] bf16 (LDS-tiled) ----
        const int co = blk - 1600;
        const float* s = w_feat + (size_t)co * 9216;
#pragma unroll
        for (int j = 0; j < 36; ++j) smem[t + j * 256] = s[t + j * 256];
        __syncthreads();
        bf16* d = w2 + (size_t)co * 9216;
#pragma unroll
        for (int j = 0; j < 36; ++j) {
            int o = t + j * 256;
            int k9 = o >> 10, ci = o & 1023;
            d[o] = __float2bfloat16(smem[ci * 9 + k9]);
        }
    } else if (blk < 2240) {
        // ---- head weights -> [n(64, pad)][512] bf16 ----
        int o = (blk - 2112) * 256 + t;        // < 64*512
        int n = o >> 9, ci = o & 511;
        float v = 0.f;
        if (n < 18)       v = wo[n * 512 + ci];
        else if (n < 54)  v = wt[(n - 18) * 512 + ci];
        wh[o] = __float2bfloat16(v);
    } else {
        // ---- zero only the halo of padded NHWC features ----
        const int tid = (blk - 2240) * 256 + t;   // < 131072
        const int chunk = tid & 127;
        const int cid = tid >> 7;                  // b*256 + e
        const int b = cid >> 8, e = cid & 255;
        int y, x;
        if (e < 156) { y = (e < 78) ? 0 : 51; x = (e < 78) ? e : e - 78; }
        else { int f = e - 156; x = (f < 50) ? 0 : 77; y = 1 + ((f < 50) ? f : f - 50); }
        bf16x8 z = {};
        *(bf16x8*)(feat_pad + (((size_t)(b * 52 + y) * 78 + x) << 10) + chunk * 8) = z;
    }
}

// ================= R15 conv: R12/R14-exact minus XCD swizzle =================
// Single variable vs R14: natural bid order. The swizzle RAISED FETCH_SIZE
// 184->287MB on this problem (R6-R8 natural vs R10-R14 swizzled; R5 A/B:
// duration flat, FETCH 177 vs 289). Natural mt-fast order keeps all XCDs on
// the same (nt,sp) panel concurrently -> B panel L2-hot + correlated A reuse.
// Structure ledger (all <=0 on this kernel): 8-phase variants, 32x32 shape
// (conflict-free swizzle provably impossible: 32 rows -> 8 slots in 128B
// rows), 2-blk/CU retile (LDS traffic up), read-hoist, barrier semantics,
// setprio. Floors: MFMA 2483 / LDS 2560 cyc per K-tile vs 4481 measured --
// both pipes ~55%, overlap residual is 2-waves/SIMD read<->MFMA serialization,
// register-locked (244/256 regs).

#define BARRIER() __builtin_amdgcn_s_barrier()
#define VM0()     asm volatile("s_waitcnt vmcnt(0)")

__global__ __launch_bounds__(512, 2) void conv_gemm8(const bf16* __restrict__ fp,
                                                     const bf16* __restrict__ w2,
                                                     bf16* __restrict__ hout) {
    __shared__ __attribute__((aligned(16))) bf16 lds[65536];   // 128 KB

    const int bid = blockIdx.x;                // natural order (swizzle removed)
    const int mt = bid % 60;
    const int r3 = bid / 60;
    const int nt = r3 >> 1;
    const int sp = r3 & 1;
    const int ks0t = sp * NTK;                 // global K-tile base

    const int t = threadIdx.x;
    const int lane = t & 63, wid = t >> 6;
    const int wm = wid >> 2, wn = wid & 3;
    const int bHalf = wn >> 1;
    const int swz = ((t & 7) ^ ((t >> 3) & 7)) * 8;   // staging source k pre-swizzle

    const bf16* pA[2][2];
    const bf16* pB[2][2];
#pragma unroll
    for (int h = 0; h < 2; ++h)
#pragma unroll
        for (int j = 0; j < 2; ++j) {
            int m = mt * 256 + h * 128 + j * 64 + (t >> 3);
            if (m > MROWS - 1) m = MROWS - 1;
            int b = m / 3800, rr = m - b * 3800;
            int y = rr / 76, x = rr - y * 76;
            pA[h][j] = fp + (size_t)((b * 52 + y) * 78 + x) * 1024 + swz;
            int n = nt * 256 + h * 128 + j * 64 + (t >> 3);
            pB[h][j] = w2 + (size_t)n * 9216 + swz;
        }

#define STAGE_A(kts, h) do { \
        const int ko_ = (ks0t + (kts)) << 6; \
        const int k9_ = ko_ >> 10, ci0_ = ko_ & 1023; \
        const int ky_ = (k9_ * 11) >> 5, kx_ = k9_ - ky_ * 3; \
        const int aoff_ = ((ky_ * 78 + kx_) << 10) + ci0_; \
        bf16* d_ = lds + (((((kts) & 1) << 1) | (h)) << 13) + wid * 512; \
        gload16(pA[h][0] + aoff_, d_); \
        gload16(pA[h][1] + aoff_, d_ + 4096); \
    } while (0)

#define STAGE_B(kts, h) do { \
        const int ko_ = (ks0t + (kts)) << 6; \
        bf16* d_ = lds + 32768 + (((((kts) & 1) << 1) | (h)) << 13) + wid * 512; \
        gload16(pB[h][0] + ko_, d_); \
        gload16(pB[h][1] + ko_, d_ + 4096); \
    } while (0)

    const int aRowOff = (lane & 15) * 64;
    const int bRowOff = ((wn & 1) * 64 + (lane & 15)) * 64;
    const int sA0 = (((lane >> 4)    ) ^ (lane & 7)) * 8;   // kk=0 slot
    const int sA1 = (((lane >> 4) + 4) ^ (lane & 7)) * 8;   // kk=1 slot

    bf16x8 avA[2], avB[2], bvP[4];
    f32x4 acc[8][4];
#pragma unroll
    for (int i = 0; i < 8; ++i)
#pragma unroll
        for (int j = 0; j < 4; ++j) acc[i][j] = (f32x4){0.f, 0.f, 0.f, 0.f};

// load one quadrant's av pair (2 reads) for pass kk into register set S
#define LOAD_AVK(S, q, d, so) do { \
        const bf16* ab_ = lds + (((d) * 2 + wm) << 13) + (q) * 2048 + aRowOff; \
        S[0] = *(const bf16x8*)(ab_ + (so)); \
        S[1] = *(const bf16x8*)(ab_ + 1024 + (so)); \
    } while (0)

// load the 4 bv fragments (4 reads) for pass kk
#define LOAD_BVK(d, so) do { \
        const bf16* bb_ = lds + 32768 + (((d) * 2 + bHalf) << 13) + bRowOff; \
        bvP[0] = *(const bf16x8*)(bb_ + (so)); \
        bvP[1] = *(const bf16x8*)(bb_ + 1024 + (so)); \
        bvP[2] = *(const bf16x8*)(bb_ + 2048 + (so)); \
        bvP[3] = *(const bf16x8*)(bb_ + 3072 + (so)); \
    } while (0)

// one cluster: 8 MFMA (2 row-frags x 4 col-frags) for quadrant q, pass kk
#define MFMA8(q, S) do { \
        _Pragma("unroll") \
        for (int e_ = 0; e_ < 2; ++e_) \
        _Pragma("unroll") \
        for (int fn_ = 0; fn_ < 4; ++fn_) \
            acc[(q) * 2 + e_][fn_] = __builtin_amdgcn_mfma_f32_16x16x32_bf16( \
                S[e_], bvP[fn_], acc[(q) * 2 + e_][fn_], 0, 0, 0); \
    } while (0)

// One K-tile: stages under first reads' latency; two kk passes, av ping-pong;
// vmcnt(0) (free: DMA issued ~4000cyc earlier) + single boundary barrier.
#define TILE(kt, d) do { \
        const int s1_ = ((kt) + 1 < NTK) ? (kt) + 1 : 0;   /* tail: junk-but-safe */ \
        LOAD_BVK(d, sA0); LOAD_AVK(avA, 0, d, sA0); \
        STAGE_A(s1_, 0); STAGE_A(s1_, 1); \
        STAGE_B(s1_, 0); STAGE_B(s1_, 1); \
        LOAD_AVK(avB, 1, d, sA0); MFMA8(0, avA); \
        LOAD_AVK(avA, 2, d, sA0); MFMA8(1, avB); \
        LOAD_AVK(avB, 3, d, sA0); MFMA8(2, avA); \
        LOAD_AVK(avA, 0, d, sA1); MFMA8(3, avB); \
        LOAD_BVK(d, sA1); \
        LOAD_AVK(avB, 1, d, sA1); MFMA8(0, avA); \
        LOAD_AVK(avA, 2, d, sA1); MFMA8(1, avB); \
        LOAD_AVK(avB, 3, d, sA1); MFMA8(2, avA); \
                                  MFMA8(3, avB); \
        VM0(); BARRIER(); \
    } while (0)

    // -------- prologue: stage kt0 into buf0, land it --------
    STAGE_A(0, 0); STAGE_A(0, 1); STAGE_B(0, 0); STAGE_B(0, 1);
    VM0();
    BARRIER();

    // -------- main loop: 36 iterations x 2 K-tiles (static buf index) --------
    for (int i = 0; i < NTK / 2; ++i) {
        TILE(2 * i,     0);
        TILE(2 * i + 1, 1);
    }

    // -------- epilogue: raw bf16 partial -> slot sp --------
    const int mb = mt * 256 + wm * 128 + ((lane >> 4) << 2);
    const int nb = nt * 256 + wn * 64 + (lane & 15);
    bf16* hd = hout + (size_t)sp * HSLOT2;
#pragma unroll
    for (int fm = 0; fm < 8; ++fm) {
#pragma unroll
        for (int fn = 0; fn < 4; ++fn) {
#pragma unroll
            for (int jj = 0; jj < 4; ++jj) {
                int m = mb + fm * 16 + jj;
                if (m < MROWS)
                    hd[(size_t)m * 512 + nb + fn * 16] = __float2bfloat16(acc[fm][fn][jj]);
            }
        }
    }
}

// ---------------- fallback: 128x128 2-phase conv, RAW full-K partial -> slot 0 ----------------
__global__ __launch_bounds__(256) void conv_gemm1(const bf16* __restrict__ fp,
                                                  const bf16* __restrict__ w2,
                                                  bf16* __restrict__ hout) {
    __shared__ __attribute__((aligned(16))) bf16 Al[128 * 64];
    __shared__ __attribute__((aligned(16))) bf16 Bl[128 * 64];

    const int bid = blockIdx.x;
    const int mt = bid % MTILES;
    const int nt = bid / MTILES;
    const int t = threadIdx.x;
    const int lane = t & 63, wv = t >> 6;
    const int wr = wv >> 1, wc = wv & 1;
    const int kp8 = (((t & 7) ^ ((t >> 3) & 7))) * 8;

    const bf16* pA[4];
    const bf16* pB[4];
#pragma unroll
    for (int i = 0; i < 4; ++i) {
        int m = mt * 128 + i * 32 + (t >> 3);
        if (m > MROWS - 1) m = MROWS - 1;
        int b = m / 3800, r = m - b * 3800;
        int y = r / 76, x = r - y * 76;
        pA[i] = fp + (size_t)((b * 52 + y) * 78 + x) * 1024 + kp8;
        int n = nt * 128 + i * 32 + (t >> 3);
        pB[i] = w2 + (size_t)n * 9216 + kp8;
    }
    char* ldsA = (char*)Al + wv * 1024;
    char* ldsB = (char*)Bl + wv * 1024;

    f32x4 acc[4][4];
#pragma unroll
    for (int i = 0; i < 4; ++i)
#pragma unroll
        for (int j = 0; j < 4; ++j) acc[i][j] = (f32x4){0.f, 0.f, 0.f, 0.f};

    const bf16* aF = Al + (wr * 64 + (lane & 15)) * 64;
    const bf16* bF = Bl + (wc * 64 + (lane & 15)) * 64;
    const int so0 = (((lane >> 4)    ) ^ (lane & 7)) * 8;
    const int so1 = (((lane >> 4) + 4) ^ (lane & 7)) * 8;

    for (int ks = 0; ks < KSTEPS; ++ks) {
        const int ko = ks << 6;
        const int k9 = ko >> 10;
        const int ci0 = ko & 1023;
        const int ky = (k9 * 11) >> 5;
        const int kx = k9 - ky * 3;
        const int aoff = ((ky * 78 + kx) << 10) + ci0;
#pragma unroll
        for (int i = 0; i < 4; ++i) gload16(pA[i] + aoff, ldsA + i * 4096);
#pragma unroll
        for (int i = 0; i < 4; ++i) gload16(pB[i] + ko, ldsB + i * 4096);
        __syncthreads();
#pragma unroll
        for (int kk = 0; kk < 2; ++kk) {
            const int so = kk ? so1 : so0;
            bf16x8 av[4], bv[4];
#pragma unroll
            for (int f = 0; f < 4; ++f) av[f] = *(const bf16x8*)(aF + f * 1024 + so);
#pragma unroll
            for (int f = 0; f < 4; ++f) bv[f] = *(const bf16x8*)(bF + f * 1024 + so);
#pragma unroll
            for (int fm = 0; fm < 4; ++fm)
#pragma unroll
                for (int fn = 0; fn < 4; ++fn)
                    acc[fm][fn] = __builtin_amdgcn_mfma_f32_16x16x32_bf16(
                        av[fm], bv[fn], acc[fm][fn], 0, 0, 0);
        }
        __syncthreads();
    }

    const int mbase = mt * 128 + wr * 64 + ((lane >> 4) << 2);
    const int nbase = nt * 128 + wc * 64 + (lane & 15);
#pragma unroll
    for (int fn = 0; fn < 4; ++fn) {
        const int n = nbase + fn * 16;
#pragma unroll
        for (int fm = 0; fm < 4; ++fm) {
#pragma unroll
            for (int j = 0; j < 4; ++j) {
                int m = mbase + fm * 16 + j;
                if (m < MROWS)
                    hout[(size_t)m * 512 + n] = __float2bfloat16(acc[fm][fn][j]);
            }
        }
    }
}

// ---------------- 1x1 heads GEMM, fused partial-sum + bias + relu on A ----------------
// 64-row tiles x 238 blocks, 128 threads (2 waves).
// NSLOT=2: A = relu(p0 + p1 + b_feat);  NSLOT=1: A = relu(p0 + b_feat)
template<int NSLOT>
__global__ __launch_bounds__(128) void head_gemm(const bf16* __restrict__ p,
                                                 const bf16* __restrict__ wh,
                                                 const float* __restrict__ bfeat,
                                                 const float* __restrict__ bo,
                                                 const float* __restrict__ bt,
                                                 float* __restrict__ out) {
    __shared__ __attribute__((aligned(16))) bf16 Ah[2][64 * 64];   // dbuf, 16KB
    __shared__ __attribute__((aligned(16))) bf16 Bh[64 * 512];     // 64KB

    const int mt = blockIdx.x;                 // 238 tiles of 64 rows
    const int t = threadIdx.x;                 // 128 threads, 2 waves
    const int lane = t & 63, wv = t >> 6;
    const int s = t & 7;                       // k-slot 0..7
    const int rg = t >> 3;                     // row 0..15 within 16-row group

    {   // preload all head weights via async DMA: 2 waves x 32 rows (1 row/gload)
        char* lb = (char*)Bh + wv * 1024;
#pragma unroll
        for (int i = 0; i < 32; ++i) {
            const int row = i * 2 + wv;
            const bf16* src = wh + (size_t)row * 512 + (size_t)(lane ^ (row & 7)) * 8;
            gload16(src, lb + i * 2048);
        }
    }

    // A staging coords: rows m = mt*64 + i*16 + rg, logical k-chunk s
    size_t aoff[4];
#pragma unroll
    for (int i = 0; i < 4; ++i) {
        int m = mt * 64 + i * 16 + rg;
        if (m > MROWS - 1) m = MROWS - 1;
        aoff[i] = (size_t)m * 512 + s * 8;
    }
    const int wswz = (s ^ (rg & 7)) * 8;       // physical slot for ds_write

    f32x4 acc[2][4];
#pragma unroll
    for (int i = 0; i < 2; ++i)
#pragma unroll
        for (int j = 0; j < 4; ++j) acc[i][j] = (f32x4){0.f, 0.f, 0.f, 0.f};

    const bf16* bF = Bh + (lane & 15) * 512;
    const int so0 = (((lane >> 4)    ) ^ (lane & 7)) * 8;
    const int so1 = (((lane >> 4) + 4) ^ (lane & 7)) * 8;

    for (int ks = 0; ks < 8; ++ks) {
        const int ko = ks << 6;
        const int buf = ks & 1;
        // ---- reg-stage: load partials, sum + bias + relu, swizzled ds_write ----
        f32x4 b0 = *(const f32x4*)(bfeat + ko + s * 8);
        f32x4 b1 = *(const f32x4*)(bfeat + ko + s * 8 + 4);
#pragma unroll
        for (int i = 0; i < 4; ++i) {
            bf16x8 v0 = *(const bf16x8*)(p + aoff[i] + ko);
            bf16x8 r;
            if (NSLOT == 2) {
                bf16x8 v1 = *(const bf16x8*)(p + HSLOT2 + aoff[i] + ko);
#pragma unroll
                for (int j = 0; j < 8; ++j) {
                    float v = (float)v0[j] + (float)v1[j] + (j < 4 ? b0[j] : b1[j - 4]);
                    r[j] = (__bf16)(v < 0.f ? 0.f : v);
                }
            } else {
#pragma unroll
                for (int j = 0; j < 8; ++j) {
                    float v = (float)v0[j] + (j < 4 ? b0[j] : b1[j - 4]);
                    r[j] = (__bf16)(v < 0.f ? 0.f : v);
                }
            }
            *(bf16x8*)(&Ah[buf][(i * 16 + rg) * 64 + wswz]) = r;
        }
        __syncthreads();                       // writes visible; also drains Bh DMA on ks=0
        // ---- MFMA on buf ----
        const bf16* aF = &Ah[buf][(wv * 32 + (lane & 15)) * 64];
#pragma unroll
        for (int kk = 0; kk < 2; ++kk) {
            const int so = kk ? so1 : so0;
            bf16x8 av[2], bv[4];
#pragma unroll
            for (int f = 0; f < 2; ++f) av[f] = *(const bf16x8*)(aF + f * 1024 + so);
#pragma unroll
            for (int f = 0; f < 4; ++f) bv[f] = *(const bf16x8*)(bF + f * 8192 + ko + so);
#pragma unroll
            for (int fm = 0; fm < 2; ++fm)
#pragma unroll
                for (int fn = 0; fn < 4; ++fn)
                    acc[fm][fn] = __builtin_amdgcn_mfma_f32_16x16x32_bf16(
                        av[fm], bv[fn], acc[fm][fn], 0, 0, 0);
        }
    }

    // epilogue: out0[b*68400 + r*18 + n] (n<18), out1 at +273600: [b*136800 + r*36 + n-18]
#pragma unroll
    for (int fn = 0; fn < 4; ++fn) {
        const int n = fn * 16 + (lane & 15);
        if (n >= 54) continue;
        const float bb = (n < 18) ? bo[n] : bt[n - 18];
#pragma unroll
        for (int fm = 0; fm < 2; ++fm) {
#pragma unroll
            for (int j = 0; j < 4; ++j) {
                int m = mt * 64 + wv * 32 + fm * 16 + ((lane >> 4) << 2) + j;
                if (m < MROWS) {
                    int b = m / 3800, r = m - b * 3800;
                    float v = acc[fm][fn][j] + bb;
                    if (n < 18) out[(size_t)b * 68400 + r * 18 + n] = v;
                    else        out[273600 + (size_t)b * 136800 + r * 36 + (n - 18)] = v;
                }
            }
        }
    }
}

extern "C" void kernel_launch(void* const* d_in, const int* in_sizes, int n_in,
                              void* d_out, int out_size, void* d_ws, size_t ws_size,
                              hipStream_t stream) {
    const float* features = (const float*)d_in[0];
    const float* w_feat   = (const float*)d_in[1];
    const float* b_feat   = (const float*)d_in[2];
    const float* w_obj    = (const float*)d_in[3];
    const float* b_obj    = (const float*)d_in[4];
    const float* w_tr     = (const float*)d_in[5];
    const float* b_tr     = (const float*)d_in[6];
    float* out = (float*)d_out;

    char* ws = (char*)d_ws;
    bf16* feat_pad = (bf16*)(ws);              // 33,226,752 B
    bf16* w2       = (bf16*)(ws + 33226752);   //  9,437,184 B
    bf16* wh       = (bf16*)(ws + 42663936);   //     65,536 B
    bf16* hbuf     = (bf16*)(ws + 42729472);   // 2 slots x 15,728,640 B -> total 74,186,752 B

    preprocess<<<dim3(2752), dim3(256), 0, stream>>>(features, w_feat, w_obj, w_tr,
                                                     feat_pad, w2, wh);

    if (ws_size >= 74186752ull) {
        conv_gemm8<<<dim3(240), dim3(512), 0, stream>>>(feat_pad, w2, hbuf);
        head_gemm<2><<<dim3(MTILE2), dim3(128), 0, stream>>>(hbuf, wh, b_feat, b_obj, b_tr, out);
    } else {
        conv_gemm1<<<dim3(MTILES * 4), dim3(256), 0, stream>>>(feat_pad, w2, hbuf);
        head_gemm<1><<<dim3(MTILE2), dim3(128), 0, stream>>>(hbuf, wh, b_feat, b_obj, b_tr, out);
    }
}